// Round 15
// baseline (5709.697 us; speedup 1.0000x reference)
//
#include <hip/hip_runtime.h>
#include <math.h>

constexpr int D = 64;      // input / output feature dim
constexpr int H = 128;     // GRU hidden dim
constexpr int MAXLEN = 512;
constexpr int MSEQ = 8;    // sequences per block (2x N-col duplication)
constexpr int NTV = 2048;  // ablation-variant step count (4x natural max)

typedef __attribute__((ext_vector_type(8))) short short8;  // 8 bf16 = 4 VGPRs
typedef __attribute__((ext_vector_type(4))) float f32x4;   // MFMA accumulator

__device__ __forceinline__ short f2bf(float f) {
    unsigned u = __float_as_uint(f);
    u += 0x7fffu + ((u >> 16) & 1u);
    return (short)(u >> 16);
}
__device__ __forceinline__ unsigned cvtpk(float a, float b) {
    unsigned r;
    asm volatile("v_cvt_pk_bf16_f32 %0, %1, %2" : "=v"(r) : "v"(a), "v"(b));
    return r;
}
__device__ __forceinline__ short8 pack8(float4 a, float4 b) {
    short8 r;
    r[0]=f2bf(a.x); r[1]=f2bf(a.y); r[2]=f2bf(a.z); r[3]=f2bf(a.w);
    r[4]=f2bf(b.x); r[5]=f2bf(b.y); r[6]=f2bf(b.z); r[7]=f2bf(b.w);
    return r;
}
__device__ __forceinline__ float rcp_(float x) { return __builtin_amdgcn_rcpf(x); }
__device__ __forceinline__ float sig_(float v) { return rcp_(1.0f + __expf(-v)); }
__device__ __forceinline__ float tanh_(float v) {
    float a = fabsf(v);
    float e = __expf(2.0f * a);
    float t = 1.0f - 2.0f * rcp_(e + 1.0f);
    return copysignf(t, v);
}
__device__ __forceinline__ void lgkm_barrier() {
    asm volatile("s_waitcnt lgkmcnt(0)\n\ts_barrier" ::: "memory");
}
__device__ __forceinline__ void lgkm_only() {
    asm volatile("s_waitcnt lgkmcnt(0)" ::: "memory");
}

#define MFMA(a,b,c) __builtin_amdgcn_mfma_f32_16x16x32_bf16((a),(b),(c),0,0,0)

// ===========================================================================
// REAL kernel: r14 gru_p4 verbatim (passing, 341.6 us). Writes d_out.
// ===========================================================================
__global__ __launch_bounds__(256, 1)
void gru_p4(const float* __restrict__ x,
            const int* __restrict__ offsets,
            const float* __restrict__ W_ih,
            const float* __restrict__ W_hh,
            const float* __restrict__ W_dense,
            const float* __restrict__ b_dense,
            float* __restrict__ out,
            int B, int T)
{
    const int bb   = blockIdx.x;
    const int tid  = threadIdx.x;
    const int w    = tid >> 6;
    const int l    = tid & 63;
    const int s    = l & 15;
    const int q    = l >> 4;
    const int sq   = s & 7;
    const int hsel = s >> 3;

    __shared__ __align__(16) short h_bf[2][MSEQ * H];
    __shared__ __align__(16) short x_bf[2][MSEQ * D];
    __shared__ int slen[MSEQ], sstart[MSEQ];
    __shared__ float h_f32[MSEQ][H];

    if (tid < MSEQ) {
        int sg = bb * MSEQ + tid;
        int st = 0, en = 1;
        if (sg < B) { st = offsets[sg]; en = (sg + 1 < B) ? offsets[sg + 1] : T; }
        int ln = en - st;
        ln = max(1, min(ln, MAXLEN));
        sstart[tid] = st; slen[tid] = ln;
    }
    {
        int* hz = (int*)h_bf[0];
        hz[tid] = 0; hz[tid + 256] = 0;
    }
    __syncthreads();

    int nt = 1;
#pragma unroll
    for (int i = 0; i < MSEQ; ++i) nt = max(nt, slen[i]);

    short8 Wh[3][2][4];
    short8 Wi[3][2][2];
#pragma unroll
    for (int g = 0; g < 3; ++g) {
#pragma unroll
        for (int u = 0; u < 2; ++u) {
            const int grow = g * H + w * 32 + u * 16 + s;
            const float* ph = W_hh + (size_t)grow * H + q * 8;
#pragma unroll
            for (int kt = 0; kt < 4; ++kt)
                Wh[g][u][kt] = pack8(*(const float4*)(ph + kt * 32),
                                     *(const float4*)(ph + kt * 32 + 4));
            const float* pi = W_ih + (size_t)grow * D + q * 8;
#pragma unroll
            for (int kt = 0; kt < 2; ++kt)
                Wi[g][u][kt] = pack8(*(const float4*)(pi + kt * 32),
                                     *(const float4*)(pi + kt * 32 + 4));
        }
    }

    int hoff[4], xoff[2], woff[2];
#pragma unroll
    for (int kt = 0; kt < 4; ++kt) hoff[kt] = sq * 256 + (((kt * 4 + q) ^ sq) << 4);
#pragma unroll
    for (int kt = 0; kt < 2; ++kt) xoff[kt] = sq * 128 + (((kt * 4 + q) ^ sq) << 4);
#pragma unroll
    for (int u = 0; u < 2; ++u)
        woff[u] = sq * 256 + ((((4 * w) + (2 * u) + (q >> 1)) ^ sq) << 4)
                + ((q & 1) << 3) + (hsel << 2);

    const int ss  = tid >> 5;
    const int pxx = tid & 31;
    const int st_x = sstart[ss];
    const int ln_x = slen[ss];
    const float* xg = x + (size_t)st_x * D + pxx * 2;
    const int xwoff = ss * 128 + (((pxx >> 2) ^ ss) << 4) + ((pxx & 3) << 2);

    {
        float2 v0 = *(const float2*)xg;
        float2 v1 = *(const float2*)(xg + (size_t)min(1, ln_x - 1) * D);
        *(unsigned*)((char*)x_bf[0] + xwoff) = cvtpk(v0.x, v0.y);
        *(unsigned*)((char*)x_bf[1] + xwoff) = cvtpk(v1.x, v1.y);
    }
    float2 xpf = *(const float2*)(xg + (size_t)min(2, ln_x - 1) * D);

    const int ln_s = slen[sq];
    float h00 = 0.f, h01 = 0.f;
    float h10 = 0.f, h11 = 0.f;

    __syncthreads();

    const f32x4 zf = {0.f, 0.f, 0.f, 0.f};
    f32x4 gr[2], gz[2], gn[2];
    {
        short8 bx0[2];
#pragma unroll
        for (int kt = 0; kt < 2; ++kt)
            bx0[kt] = *(const short8*)((const char*)x_bf[0] + xoff[kt]);
#pragma unroll
        for (int u = 0; u < 2; ++u) {
            gr[u] = MFMA(Wi[0][u][0], bx0[0], zf);
            gr[u] = MFMA(Wi[0][u][1], bx0[1], gr[u]);
            gz[u] = MFMA(Wi[1][u][0], bx0[0], zf);
            gz[u] = MFMA(Wi[1][u][1], bx0[1], gz[u]);
            gn[u] = MFMA(Wi[2][u][0], bx0[0], zf);
            gn[u] = MFMA(Wi[2][u][1], bx0[1], gn[u]);
        }
    }
    lgkm_barrier();

    for (int t = 0; t < nt; ++t) {
        const int p = t & 1;
        const char* hb = (const char*)h_bf[p];
        const char* xb = (const char*)x_bf[p ^ 1];

        short8 bh[4], bxn[2];
#pragma unroll
        for (int kt = 0; kt < 4; ++kt) bh[kt] = *(const short8*)(hb + hoff[kt]);
#pragma unroll
        for (int kt = 0; kt < 2; ++kt) bxn[kt] = *(const short8*)(xb + xoff[kt]);

        f32x4 chn[2];
#pragma unroll
        for (int u = 0; u < 2; ++u) {
            chn[u] = MFMA(Wh[2][u][0], bh[0], zf);
#pragma unroll
            for (int kt = 1; kt < 4; ++kt) chn[u] = MFMA(Wh[2][u][kt], bh[kt], chn[u]);
#pragma unroll
            for (int kt = 0; kt < 4; ++kt) {
                gr[u] = MFMA(Wh[0][u][kt], bh[kt], gr[u]);
                gz[u] = MFMA(Wh[1][u][kt], bh[kt], gz[u]);
            }
        }

        const bool upd = (t < ln_s);
        {
            float vr0 = hsel ? gr[0][2] : gr[0][0], vr1 = hsel ? gr[0][3] : gr[0][1];
            float vz0 = hsel ? gz[0][2] : gz[0][0], vz1 = hsel ? gz[0][3] : gz[0][1];
            float vi0 = hsel ? gn[0][2] : gn[0][0], vi1 = hsel ? gn[0][3] : gn[0][1];
            float vh0 = hsel ? chn[0][2] : chn[0][0], vh1 = hsel ? chn[0][3] : chn[0][1];
            float r0 = sig_(vr0), r1 = sig_(vr1);
            float z0 = sig_(vz0), z1 = sig_(vz1);
            float n0 = tanh_(vi0 + r0 * vh0);
            float n1 = tanh_(vi1 + r1 * vh1);
            float a0 = (1.0f - z0) * n0 + z0 * h00;
            float a1 = (1.0f - z1) * n1 + z1 * h01;
            h00 = upd ? a0 : h00;
            h01 = upd ? a1 : h01;
        }
        {
            float vr0 = hsel ? gr[1][2] : gr[1][0], vr1 = hsel ? gr[1][3] : gr[1][1];
            float vz0 = hsel ? gz[1][2] : gz[1][0], vz1 = hsel ? gz[1][3] : gz[1][1];
            float vi0 = hsel ? gn[1][2] : gn[1][0], vi1 = hsel ? gn[1][3] : gn[1][1];
            float vh0 = hsel ? chn[1][2] : chn[1][0], vh1 = hsel ? chn[1][3] : chn[1][1];
            float r0 = sig_(vr0), r1 = sig_(vr1);
            float z0 = sig_(vz0), z1 = sig_(vz1);
            float n0 = tanh_(vi0 + r0 * vh0);
            float n1 = tanh_(vi1 + r1 * vh1);
            float a0 = (1.0f - z0) * n0 + z0 * h10;
            float a1 = (1.0f - z1) * n1 + z1 * h11;
            h10 = upd ? a0 : h10;
            h11 = upd ? a1 : h11;
        }

        *(unsigned*)((char*)h_bf[p ^ 1] + woff[0]) = cvtpk(h00, h01);
        *(unsigned*)((char*)h_bf[p ^ 1] + woff[1]) = cvtpk(h10, h11);

#pragma unroll
        for (int u = 0; u < 2; ++u) {
            gr[u] = MFMA(Wi[0][u][0], bxn[0], zf);
            gr[u] = MFMA(Wi[0][u][1], bxn[1], gr[u]);
            gz[u] = MFMA(Wi[1][u][0], bxn[0], zf);
            gz[u] = MFMA(Wi[1][u][1], bxn[1], gz[u]);
            gn[u] = MFMA(Wi[2][u][0], bxn[0], zf);
            gn[u] = MFMA(Wi[2][u][1], bxn[1], gn[u]);
        }

        *(unsigned*)((char*)x_bf[p] + xwoff) = cvtpk(xpf.x, xpf.y);
        {
            const int tn = (t + 3 < ln_x) ? t + 3 : ln_x - 1;
            xpf = *(const float2*)(xg + (size_t)tn * D);
        }

        lgkm_barrier();
    }

    {
        float2 hv0 = { h00, h01 };
        float2 hv1 = { h10, h11 };
        *(float2*)&h_f32[sq][w * 32 + 0  + q * 4 + 2 * hsel] = hv0;
        *(float2*)&h_f32[sq][w * 32 + 16 + q * 4 + 2 * hsel] = hv1;
    }
    __syncthreads();

    {
        const int s2 = tid >> 5;
        const int cb = tid & 31;
        float acc0 = b_dense[cb];
        float acc1 = b_dense[cb + 32];
        const float* w0 = W_dense + (size_t)cb * H;
        const float* w1 = W_dense + (size_t)(cb + 32) * H;
#pragma unroll
        for (int j = 0; j < H; j += 4) {
            float4 hv = *(const float4*)&h_f32[s2][j];
            float4 a0 = *(const float4*)(w0 + j);
            float4 a1 = *(const float4*)(w1 + j);
            acc0 += hv.x*a0.x + hv.y*a0.y + hv.z*a0.z + hv.w*a0.w;
            acc1 += hv.x*a1.x + hv.y*a1.y + hv.z*a1.z + hv.w*a1.w;
        }
        float s2q = acc0 * acc0 + acc1 * acc1;
#pragma unroll
        for (int off = 16; off >= 1; off >>= 1) s2q += __shfl_xor(s2q, off);
        float invn = 1.0f / fmaxf(sqrtf(s2q), 1e-12f);
        int sg = bb * MSEQ + s2;
        if (sg < B) {
            out[(size_t)sg * D + cb]      = acc0 * invn;
            out[(size_t)sg * D + cb + 32] = acc1 * invn;
        }
    }
}

// ===========================================================================
// ABLATION variants (write d_ws only; NTV=2048 steps for visibility in the
// per-dispatch rocprof table). V0=full, V1=no-gate, V2=no-MFMA, V3=no-DS-read,
// V4=no-barrier. DCE guarded per rule #17 (sinks keep skipped inputs live).
// ===========================================================================
template<int V>
__global__ __launch_bounds__(256, 1)
void gru_abl(const float* __restrict__ x,
             const int* __restrict__ offsets,
             const float* __restrict__ W_ih,
             const float* __restrict__ W_hh,
             float* __restrict__ ws,
             int B, int T)
{
    const int bb   = blockIdx.x;
    const int tid  = threadIdx.x;
    const int w    = tid >> 6;
    const int l    = tid & 63;
    const int s    = l & 15;
    const int q    = l >> 4;
    const int sq   = s & 7;
    const int hsel = s >> 3;

    __shared__ __align__(16) short h_bf[2][MSEQ * H];
    __shared__ __align__(16) short x_bf[2][MSEQ * D];
    __shared__ int slen[MSEQ], sstart[MSEQ];

    if (tid < MSEQ) {
        int sg = bb * MSEQ + tid;
        int st = 0, en = 1;
        if (sg < B) { st = offsets[sg]; en = (sg + 1 < B) ? offsets[sg + 1] : T; }
        int ln = en - st;
        ln = max(1, min(ln, MAXLEN));
        sstart[tid] = st; slen[tid] = ln;
    }
    {
        int* hz = (int*)h_bf[0];
        hz[tid] = 0; hz[tid + 256] = 0;
    }
    __syncthreads();

    short8 Wh[3][2][4];
    short8 Wi[3][2][2];
#pragma unroll
    for (int g = 0; g < 3; ++g) {
#pragma unroll
        for (int u = 0; u < 2; ++u) {
            const int grow = g * H + w * 32 + u * 16 + s;
            const float* ph = W_hh + (size_t)grow * H + q * 8;
#pragma unroll
            for (int kt = 0; kt < 4; ++kt)
                Wh[g][u][kt] = pack8(*(const float4*)(ph + kt * 32),
                                     *(const float4*)(ph + kt * 32 + 4));
            const float* pi = W_ih + (size_t)grow * D + q * 8;
#pragma unroll
            for (int kt = 0; kt < 2; ++kt)
                Wi[g][u][kt] = pack8(*(const float4*)(pi + kt * 32),
                                     *(const float4*)(pi + kt * 32 + 4));
        }
    }

    int hoff[4], xoff[2], woff[2];
#pragma unroll
    for (int kt = 0; kt < 4; ++kt) hoff[kt] = sq * 256 + (((kt * 4 + q) ^ sq) << 4);
#pragma unroll
    for (int kt = 0; kt < 2; ++kt) xoff[kt] = sq * 128 + (((kt * 4 + q) ^ sq) << 4);
#pragma unroll
    for (int u = 0; u < 2; ++u)
        woff[u] = sq * 256 + ((((4 * w) + (2 * u) + (q >> 1)) ^ sq) << 4)
                + ((q & 1) << 3) + (hsel << 2);

    const int ss  = tid >> 5;
    const int pxx = tid & 31;
    const int st_x = sstart[ss];
    const int ln_x = slen[ss];
    const float* xg = x + (size_t)st_x * D + pxx * 2;
    const int xwoff = ss * 128 + (((pxx >> 2) ^ ss) << 4) + ((pxx & 3) << 2);

    {
        float2 v0 = *(const float2*)xg;
        float2 v1 = *(const float2*)(xg + (size_t)min(1, ln_x - 1) * D);
        *(unsigned*)((char*)x_bf[0] + xwoff) = cvtpk(v0.x, v0.y);
        *(unsigned*)((char*)x_bf[1] + xwoff) = cvtpk(v1.x, v1.y);
    }
    float2 xpf = *(const float2*)(xg + (size_t)min(2, ln_x - 1) * D);

    const int ln_s = slen[sq];
    float h00 = 0.f, h01 = 0.f, h10 = 0.f, h11 = 0.f;
    int snk = 0;

    __syncthreads();

    const f32x4 zf = {0.f, 0.f, 0.f, 0.f};
    f32x4 gr[2], gz[2], gn[2];
#pragma unroll
    for (int u = 0; u < 2; ++u) { gr[u] = zf; gz[u] = zf; gn[u] = zf; }
    if (V != 2) {   // prologue gi_0
        short8 bx0[2];
#pragma unroll
        for (int kt = 0; kt < 2; ++kt)
            bx0[kt] = (V == 3) ? Wi[0][0][kt]
                               : *(const short8*)((const char*)x_bf[0] + xoff[kt]);
#pragma unroll
        for (int u = 0; u < 2; ++u) {
            gr[u] = MFMA(Wi[0][u][0], bx0[0], zf);
            gr[u] = MFMA(Wi[0][u][1], bx0[1], gr[u]);
            gz[u] = MFMA(Wi[1][u][0], bx0[0], zf);
            gz[u] = MFMA(Wi[1][u][1], bx0[1], gz[u]);
            gn[u] = MFMA(Wi[2][u][0], bx0[0], zf);
            gn[u] = MFMA(Wi[2][u][1], bx0[1], gn[u]);
        }
    }
    lgkm_barrier();

    for (int t = 0; t < NTV; ++t) {
        const int p = t & 1;
        const char* hb = (const char*)h_bf[p];
        const char* xb = (const char*)x_bf[p ^ 1];

        short8 bh[4], bxn[2];
        if (V != 3) {
#pragma unroll
            for (int kt = 0; kt < 4; ++kt) bh[kt] = *(const short8*)(hb + hoff[kt]);
#pragma unroll
            for (int kt = 0; kt < 2; ++kt) bxn[kt] = *(const short8*)(xb + xoff[kt]);
        } else {
#pragma unroll
            for (int kt = 0; kt < 4; ++kt) bh[kt] = Wh[0][0][kt];
#pragma unroll
            for (int kt = 0; kt < 2; ++kt) bxn[kt] = Wi[0][0][kt];
        }

        f32x4 chn[2] = { zf, zf };
        if (V != 2) {
#pragma unroll
            for (int u = 0; u < 2; ++u) {
                chn[u] = MFMA(Wh[2][u][0], bh[0], zf);
#pragma unroll
                for (int kt = 1; kt < 4; ++kt) chn[u] = MFMA(Wh[2][u][kt], bh[kt], chn[u]);
#pragma unroll
                for (int kt = 0; kt < 4; ++kt) {
                    gr[u] = MFMA(Wh[0][u][kt], bh[kt], gr[u]);
                    gz[u] = MFMA(Wh[1][u][kt], bh[kt], gz[u]);
                }
            }
        } else {
            // keep the ds_reads live without the matrix pipe (rule #17)
            snk ^= (int)bh[0][0] ^ (int)bh[1][1] ^ (int)bh[2][2] ^ (int)bh[3][3]
                 ^ (int)bxn[0][0] ^ (int)bxn[1][1];
        }

        const bool upd = (t < ln_s);
        if (V != 1) {
            float vr0, vr1, vz0, vz1, vi0, vi1, vh0, vh1;
            if (V == 2) {   // synthesize gate inputs from h regs (keeps dep + trans)
                vr0 = fmaf(h00, 1.10f, -0.2f); vr1 = fmaf(h01, 0.90f,  0.3f);
                vz0 = fmaf(h10, 1.05f, -0.1f); vz1 = fmaf(h11, 0.95f,  0.2f);
                vi0 = fmaf(h00, 0.97f,  0.1f); vi1 = fmaf(h01, 1.02f, -0.3f);
                vh0 = fmaf(h10, 1.01f,  0.2f); vh1 = fmaf(h11, 0.99f, -0.1f);
            } else {
                vr0 = hsel ? gr[0][2] : gr[0][0]; vr1 = hsel ? gr[0][3] : gr[0][1];
                vz0 = hsel ? gz[0][2] : gz[0][0]; vz1 = hsel ? gz[0][3] : gz[0][1];
                vi0 = hsel ? gn[0][2] : gn[0][0]; vi1 = hsel ? gn[0][3] : gn[0][1];
                vh0 = hsel ? chn[0][2] : chn[0][0]; vh1 = hsel ? chn[0][3] : chn[0][1];
            }
            {
                float r0 = sig_(vr0), r1 = sig_(vr1);
                float z0 = sig_(vz0), z1 = sig_(vz1);
                float n0 = tanh_(vi0 + r0 * vh0);
                float n1 = tanh_(vi1 + r1 * vh1);
                float a0 = (1.0f - z0) * n0 + z0 * h00;
                float a1 = (1.0f - z1) * n1 + z1 * h01;
                h00 = upd ? a0 : h00;
                h01 = upd ? a1 : h01;
            }
            if (V == 2) {
                float vr2 = fmaf(h10, 1.08f, -0.2f), vr3 = fmaf(h11, 0.92f, 0.1f);
                float vz2 = fmaf(h00, 1.03f,  0.2f), vz3 = fmaf(h01, 0.96f,-0.2f);
                float vi2 = fmaf(h10, 0.98f, -0.1f), vi3 = fmaf(h11, 1.04f, 0.3f);
                float vh2 = fmaf(h00, 1.00f,  0.1f), vh3 = fmaf(h01, 1.01f,-0.2f);
                float r0 = sig_(vr2), r1 = sig_(vr3);
                float z0 = sig_(vz2), z1 = sig_(vz3);
                float n0 = tanh_(vi2 + r0 * vh2);
                float n1 = tanh_(vi3 + r1 * vh3);
                float a0 = (1.0f - z0) * n0 + z0 * h10;
                float a1 = (1.0f - z1) * n1 + z1 * h11;
                h10 = upd ? a0 : h10;
                h11 = upd ? a1 : h11;
            } else {
                float vr0b = hsel ? gr[1][2] : gr[1][0], vr1b = hsel ? gr[1][3] : gr[1][1];
                float vz0b = hsel ? gz[1][2] : gz[1][0], vz1b = hsel ? gz[1][3] : gz[1][1];
                float vi0b = hsel ? gn[1][2] : gn[1][0], vi1b = hsel ? gn[1][3] : gn[1][1];
                float vh0b = hsel ? chn[1][2] : chn[1][0], vh1b = hsel ? chn[1][3] : chn[1][1];
                float r0 = sig_(vr0b), r1 = sig_(vr1b);
                float z0 = sig_(vz0b), z1 = sig_(vz1b);
                float n0 = tanh_(vi0b + r0 * vh0b);
                float n1 = tanh_(vi1b + r1 * vh1b);
                float a0 = (1.0f - z0) * n0 + z0 * h10;
                float a1 = (1.0f - z1) * n1 + z1 * h11;
                h10 = upd ? a0 : h10;
                h11 = upd ? a1 : h11;
            }
        } else {
            // no-gate: cheap linear update referencing ALL accumulators (no DCE)
            h00 = 0.5f * h00 + 1e-3f * (gr[0][0] + gz[0][1]);
            h01 = 0.5f * h01 + 1e-3f * (gn[0][2] + chn[0][3]);
            h10 = 0.5f * h10 + 1e-3f * (gr[1][0] + gz[1][1]);
            h11 = 0.5f * h11 + 1e-3f * (gn[1][2] + chn[1][3]);
        }

        *(unsigned*)((char*)h_bf[p ^ 1] + woff[0]) = cvtpk(h00, h01);
        *(unsigned*)((char*)h_bf[p ^ 1] + woff[1]) = cvtpk(h10, h11);

        if (V != 2) {
#pragma unroll
            for (int u = 0; u < 2; ++u) {
                gr[u] = MFMA(Wi[0][u][0], bxn[0], zf);
                gr[u] = MFMA(Wi[0][u][1], bxn[1], gr[u]);
                gz[u] = MFMA(Wi[1][u][0], bxn[0], zf);
                gz[u] = MFMA(Wi[1][u][1], bxn[1], gz[u]);
                gn[u] = MFMA(Wi[2][u][0], bxn[0], zf);
                gn[u] = MFMA(Wi[2][u][1], bxn[1], gn[u]);
            }
        }

        *(unsigned*)((char*)x_bf[p] + xwoff) = cvtpk(xpf.x, xpf.y);
        {
            const int tn = (t + 3 < ln_x) ? t + 3 : ln_x - 1;
            xpf = *(const float2*)(xg + (size_t)tn * D);
        }

        if (V != 4) lgkm_barrier();
        else        lgkm_only();
    }

    // sink (ws only; never d_out)
    ws[(size_t)bb * 256 + tid] = h00 + h01 + h10 + h11 + (float)snk * 1e-20f;
}

extern "C" void kernel_launch(void* const* d_in, const int* in_sizes, int n_in,
                              void* d_out, int out_size, void* d_ws, size_t ws_size,
                              hipStream_t stream) {
    const float* x       = (const float*)d_in[0];
    const int*   offsets = (const int*)d_in[1];
    const float* W_ih    = (const float*)d_in[2];
    const float* W_hh    = (const float*)d_in[3];
    const float* W_dense = (const float*)d_in[4];
    const float* b_dense = (const float*)d_in[5];
    float*       out     = (float*)d_out;

    const int B = in_sizes[1];
    const int T = in_sizes[0] / D;
    const int grid = (B + MSEQ - 1) / MSEQ;

    // real kernel (writes d_out, verified r14)
    gru_p4<<<grid, 256, 0, stream>>>(x, offsets, W_ih, W_hh, W_dense, b_dense, out, B, T);

    // ablation dispatches (ws only) — diagnostic round
    if (ws_size >= (size_t)grid * 256 * 4 + 64) {
        float* ws = (float*)d_ws;
        gru_abl<0><<<grid, 256, 0, stream>>>(x, offsets, W_ih, W_hh, ws, B, T);
        gru_abl<1><<<grid, 256, 0, stream>>>(x, offsets, W_ih, W_hh, ws, B, T);
        gru_abl<2><<<grid, 256, 0, stream>>>(x, offsets, W_ih, W_hh, ws, B, T);
        gru_abl<3><<<grid, 256, 0, stream>>>(x, offsets, W_ih, W_hh, ws, B, T);
        gru_abl<4><<<grid, 256, 0, stream>>>(x, offsets, W_ih, W_hh, ws, B, T);
    }
}

// Round 16
// 2490.339 us; speedup vs baseline: 2.2927x; 2.2927x over previous
//
#include <hip/hip_runtime.h>
#include <math.h>

constexpr int D = 64;
constexpr int H = 128;
constexpr int MAXLEN = 512;
constexpr int MSEQ = 8;

typedef __attribute__((ext_vector_type(8))) short short8;
typedef __attribute__((ext_vector_type(4))) float f32x4;

__device__ __forceinline__ short f2bf(float f) {
    unsigned u = __float_as_uint(f);
    u += 0x7fffu + ((u >> 16) & 1u);
    return (short)(u >> 16);
}
__device__ __forceinline__ unsigned cvtpk(float a, float b) {
    unsigned r;
    asm volatile("v_cvt_pk_bf16_f32 %0, %1, %2" : "=v"(r) : "v"(a), "v"(b));
    return r;
}
__device__ __forceinline__ short8 pack8(float4 a, float4 b) {
    short8 r;
    r[0]=f2bf(a.x); r[1]=f2bf(a.y); r[2]=f2bf(a.z); r[3]=f2bf(a.w);
    r[4]=f2bf(b.x); r[5]=f2bf(b.y); r[6]=f2bf(b.z); r[7]=f2bf(b.w);
    return r;
}
__device__ __forceinline__ float rcp_(float x) { return __builtin_amdgcn_rcpf(x); }
__device__ __forceinline__ float sig_(float v) { return rcp_(1.0f + __expf(-v)); }
__device__ __forceinline__ float tanh_(float v) {
    float a = fabsf(v);
    float e = __expf(2.0f * a);
    float t = 1.0f - 2.0f * rcp_(e + 1.0f);
    return copysignf(t, v);
}
__device__ __forceinline__ void lgkm_barrier() {
    asm volatile("s_waitcnt lgkmcnt(0)\n\ts_barrier" ::: "memory");
}

#define MFMA(a,b,c) __builtin_amdgcn_mfma_f32_16x16x32_bf16((a),(b),(c),0,0,0)

// ===========================================================================
// REAL kernel: r14 gru_p4 verbatim (passing, 341.6 us). Writes d_out.
// ===========================================================================
__global__ __launch_bounds__(256, 1)
void gru_p4(const float* __restrict__ x,
            const int* __restrict__ offsets,
            const float* __restrict__ W_ih,
            const float* __restrict__ W_hh,
            const float* __restrict__ W_dense,
            const float* __restrict__ b_dense,
            float* __restrict__ out,
            int B, int T)
{
    const int bb   = blockIdx.x;
    const int tid  = threadIdx.x;
    const int w    = tid >> 6;
    const int l    = tid & 63;
    const int s    = l & 15;
    const int q    = l >> 4;
    const int sq   = s & 7;
    const int hsel = s >> 3;

    __shared__ __align__(16) short h_bf[2][MSEQ * H];
    __shared__ __align__(16) short x_bf[2][MSEQ * D];
    __shared__ int slen[MSEQ], sstart[MSEQ];
    __shared__ float h_f32[MSEQ][H];

    if (tid < MSEQ) {
        int sg = bb * MSEQ + tid;
        int st = 0, en = 1;
        if (sg < B) { st = offsets[sg]; en = (sg + 1 < B) ? offsets[sg + 1] : T; }
        int ln = en - st;
        ln = max(1, min(ln, MAXLEN));
        sstart[tid] = st; slen[tid] = ln;
    }
    {
        int* hz = (int*)h_bf[0];
        hz[tid] = 0; hz[tid + 256] = 0;
    }
    __syncthreads();

    int nt = 1;
#pragma unroll
    for (int i = 0; i < MSEQ; ++i) nt = max(nt, slen[i]);

    short8 Wh[3][2][4];
    short8 Wi[3][2][2];
#pragma unroll
    for (int g = 0; g < 3; ++g) {
#pragma unroll
        for (int u = 0; u < 2; ++u) {
            const int grow = g * H + w * 32 + u * 16 + s;
            const float* ph = W_hh + (size_t)grow * H + q * 8;
#pragma unroll
            for (int kt = 0; kt < 4; ++kt)
                Wh[g][u][kt] = pack8(*(const float4*)(ph + kt * 32),
                                     *(const float4*)(ph + kt * 32 + 4));
            const float* pi = W_ih + (size_t)grow * D + q * 8;
#pragma unroll
            for (int kt = 0; kt < 2; ++kt)
                Wi[g][u][kt] = pack8(*(const float4*)(pi + kt * 32),
                                     *(const float4*)(pi + kt * 32 + 4));
        }
    }

    int hoff[4], xoff[2], woff[2];
#pragma unroll
    for (int kt = 0; kt < 4; ++kt) hoff[kt] = sq * 256 + (((kt * 4 + q) ^ sq) << 4);
#pragma unroll
    for (int kt = 0; kt < 2; ++kt) xoff[kt] = sq * 128 + (((kt * 4 + q) ^ sq) << 4);
#pragma unroll
    for (int u = 0; u < 2; ++u)
        woff[u] = sq * 256 + ((((4 * w) + (2 * u) + (q >> 1)) ^ sq) << 4)
                + ((q & 1) << 3) + (hsel << 2);

    const int ss  = tid >> 5;
    const int pxx = tid & 31;
    const int st_x = sstart[ss];
    const int ln_x = slen[ss];
    const float* xg = x + (size_t)st_x * D + pxx * 2;
    const int xwoff = ss * 128 + (((pxx >> 2) ^ ss) << 4) + ((pxx & 3) << 2);

    {
        float2 v0 = *(const float2*)xg;
        float2 v1 = *(const float2*)(xg + (size_t)min(1, ln_x - 1) * D);
        *(unsigned*)((char*)x_bf[0] + xwoff) = cvtpk(v0.x, v0.y);
        *(unsigned*)((char*)x_bf[1] + xwoff) = cvtpk(v1.x, v1.y);
    }
    float2 xpf = *(const float2*)(xg + (size_t)min(2, ln_x - 1) * D);

    const int ln_s = slen[sq];
    float h00 = 0.f, h01 = 0.f;
    float h10 = 0.f, h11 = 0.f;

    __syncthreads();

    const f32x4 zf = {0.f, 0.f, 0.f, 0.f};
    f32x4 gr[2], gz[2], gn[2];
    {
        short8 bx0[2];
#pragma unroll
        for (int kt = 0; kt < 2; ++kt)
            bx0[kt] = *(const short8*)((const char*)x_bf[0] + xoff[kt]);
#pragma unroll
        for (int u = 0; u < 2; ++u) {
            gr[u] = MFMA(Wi[0][u][0], bx0[0], zf);
            gr[u] = MFMA(Wi[0][u][1], bx0[1], gr[u]);
            gz[u] = MFMA(Wi[1][u][0], bx0[0], zf);
            gz[u] = MFMA(Wi[1][u][1], bx0[1], gz[u]);
            gn[u] = MFMA(Wi[2][u][0], bx0[0], zf);
            gn[u] = MFMA(Wi[2][u][1], bx0[1], gn[u]);
        }
    }
    lgkm_barrier();

    for (int t = 0; t < nt; ++t) {
        const int p = t & 1;
        const char* hb = (const char*)h_bf[p];
        const char* xb = (const char*)x_bf[p ^ 1];

        short8 bh[4], bxn[2];
#pragma unroll
        for (int kt = 0; kt < 4; ++kt) bh[kt] = *(const short8*)(hb + hoff[kt]);
#pragma unroll
        for (int kt = 0; kt < 2; ++kt) bxn[kt] = *(const short8*)(xb + xoff[kt]);

        f32x4 chn[2];
#pragma unroll
        for (int u = 0; u < 2; ++u) {
            chn[u] = MFMA(Wh[2][u][0], bh[0], zf);
#pragma unroll
            for (int kt = 1; kt < 4; ++kt) chn[u] = MFMA(Wh[2][u][kt], bh[kt], chn[u]);
#pragma unroll
            for (int kt = 0; kt < 4; ++kt) {
                gr[u] = MFMA(Wh[0][u][kt], bh[kt], gr[u]);
                gz[u] = MFMA(Wh[1][u][kt], bh[kt], gz[u]);
            }
        }

        const bool upd = (t < ln_s);
        {
            float vr0 = hsel ? gr[0][2] : gr[0][0], vr1 = hsel ? gr[0][3] : gr[0][1];
            float vz0 = hsel ? gz[0][2] : gz[0][0], vz1 = hsel ? gz[0][3] : gz[0][1];
            float vi0 = hsel ? gn[0][2] : gn[0][0], vi1 = hsel ? gn[0][3] : gn[0][1];
            float vh0 = hsel ? chn[0][2] : chn[0][0], vh1 = hsel ? chn[0][3] : chn[0][1];
            float r0 = sig_(vr0), r1 = sig_(vr1);
            float z0 = sig_(vz0), z1 = sig_(vz1);
            float n0 = tanh_(vi0 + r0 * vh0);
            float n1 = tanh_(vi1 + r1 * vh1);
            float a0 = (1.0f - z0) * n0 + z0 * h00;
            float a1 = (1.0f - z1) * n1 + z1 * h01;
            h00 = upd ? a0 : h00;
            h01 = upd ? a1 : h01;
        }
        {
            float vr0 = hsel ? gr[1][2] : gr[1][0], vr1 = hsel ? gr[1][3] : gr[1][1];
            float vz0 = hsel ? gz[1][2] : gz[1][0], vz1 = hsel ? gz[1][3] : gz[1][1];
            float vi0 = hsel ? gn[1][2] : gn[1][0], vi1 = hsel ? gn[1][3] : gn[1][1];
            float vh0 = hsel ? chn[1][2] : chn[1][0], vh1 = hsel ? chn[1][3] : chn[1][1];
            float r0 = sig_(vr0), r1 = sig_(vr1);
            float z0 = sig_(vz0), z1 = sig_(vz1);
            float n0 = tanh_(vi0 + r0 * vh0);
            float n1 = tanh_(vi1 + r1 * vh1);
            float a0 = (1.0f - z0) * n0 + z0 * h10;
            float a1 = (1.0f - z1) * n1 + z1 * h11;
            h10 = upd ? a0 : h10;
            h11 = upd ? a1 : h11;
        }

        *(unsigned*)((char*)h_bf[p ^ 1] + woff[0]) = cvtpk(h00, h01);
        *(unsigned*)((char*)h_bf[p ^ 1] + woff[1]) = cvtpk(h10, h11);

#pragma unroll
        for (int u = 0; u < 2; ++u) {
            gr[u] = MFMA(Wi[0][u][0], bxn[0], zf);
            gr[u] = MFMA(Wi[0][u][1], bxn[1], gr[u]);
            gz[u] = MFMA(Wi[1][u][0], bxn[0], zf);
            gz[u] = MFMA(Wi[1][u][1], bxn[1], gz[u]);
            gn[u] = MFMA(Wi[2][u][0], bxn[0], zf);
            gn[u] = MFMA(Wi[2][u][1], bxn[1], gn[u]);
        }

        *(unsigned*)((char*)x_bf[p] + xwoff) = cvtpk(xpf.x, xpf.y);
        {
            const int tn = (t + 3 < ln_x) ? t + 3 : ln_x - 1;
            xpf = *(const float2*)(xg + (size_t)tn * D);
        }

        lgkm_barrier();
    }

    {
        float2 hv0 = { h00, h01 };
        float2 hv1 = { h10, h11 };
        *(float2*)&h_f32[sq][w * 32 + 0  + q * 4 + 2 * hsel] = hv0;
        *(float2*)&h_f32[sq][w * 32 + 16 + q * 4 + 2 * hsel] = hv1;
    }
    __syncthreads();

    {
        const int s2 = tid >> 5;
        const int cb = tid & 31;
        float acc0 = b_dense[cb];
        float acc1 = b_dense[cb + 32];
        const float* w0 = W_dense + (size_t)cb * H;
        const float* w1 = W_dense + (size_t)(cb + 32) * H;
#pragma unroll
        for (int j = 0; j < H; j += 4) {
            float4 hv = *(const float4*)&h_f32[s2][j];
            float4 a0 = *(const float4*)(w0 + j);
            float4 a1 = *(const float4*)(w1 + j);
            acc0 += hv.x*a0.x + hv.y*a0.y + hv.z*a0.z + hv.w*a0.w;
            acc1 += hv.x*a1.x + hv.y*a1.y + hv.z*a1.z + hv.w*a1.w;
        }
        float s2q = acc0 * acc0 + acc1 * acc1;
#pragma unroll
        for (int off = 16; off >= 1; off >>= 1) s2q += __shfl_xor(s2q, off);
        float invn = 1.0f / fmaxf(sqrtf(s2q), 1e-12f);
        int sg = bb * MSEQ + s2;
        if (sg < B) {
            out[(size_t)sg * D + cb]      = acc0 * invn;
            out[(size_t)sg * D + cb + 32] = acc1 * invn;
        }
    }
}

// ===========================================================================
// ISOLATION kernels — distinct names so the rocprof top-5 table identifies
// them. Each runs ONE phase of the r14 loop + lgkm_barrier, NTV uniform steps,
// grid 256 x 256 threads (1 block/CU, 1 wave/SIMD) matching the real config.
// per-step cyc = dur_us * 2400 / NTV.
// ===========================================================================

// ---- iso_mfma: 36 MFMAs/step with r14's exact chain structure ----
__global__ __launch_bounds__(256, 1)
void iso_mfma(const float* __restrict__ W_ih,
              const float* __restrict__ W_hh,
              float* __restrict__ ws, int NTV)
{
    const int tid = threadIdx.x;
    const int w   = tid >> 6;
    const int l   = tid & 63;
    const int s   = l & 15;
    const int q   = l >> 4;

    short8 Wh[3][2][4];
    short8 Wi[3][2][2];
#pragma unroll
    for (int g = 0; g < 3; ++g) {
#pragma unroll
        for (int u = 0; u < 2; ++u) {
            const int grow = g * H + w * 32 + u * 16 + s;
            const float* ph = W_hh + (size_t)grow * H + q * 8;
#pragma unroll
            for (int kt = 0; kt < 4; ++kt)
                Wh[g][u][kt] = pack8(*(const float4*)(ph + kt * 32),
                                     *(const float4*)(ph + kt * 32 + 4));
            const float* pi = W_ih + (size_t)grow * D + q * 8;
#pragma unroll
            for (int kt = 0; kt < 2; ++kt)
                Wi[g][u][kt] = pack8(*(const float4*)(pi + kt * 32),
                                     *(const float4*)(pi + kt * 32 + 4));
        }
    }

    // fake B-operands from weight regs; perturbed per step (defeats LICM)
    short8 bh[4], bx[2];
#pragma unroll
    for (int kt = 0; kt < 4; ++kt) bh[kt] = Wh[0][0][kt];
#pragma unroll
    for (int kt = 0; kt < 2; ++kt) bx[kt] = Wi[0][0][kt];

    const f32x4 zf = {0.f, 0.f, 0.f, 0.f};
    f32x4 gr[2], gz[2], gn[2];
#pragma unroll
    for (int u = 0; u < 2; ++u) { gr[u] = zf; gz[u] = zf; gn[u] = zf; }
    float h00 = 0.f, h01 = 0.f;

    __syncthreads();

    for (int t = 0; t < NTV; ++t) {
        bh[0][0] = (short)(bh[0][0] ^ (short)(t & 1));   // step perturbation
        f32x4 chn[2];
#pragma unroll
        for (int u = 0; u < 2; ++u) {
            chn[u] = MFMA(Wh[2][u][0], bh[0], zf);
#pragma unroll
            for (int kt = 1; kt < 4; ++kt) chn[u] = MFMA(Wh[2][u][kt], bh[kt], chn[u]);
#pragma unroll
            for (int kt = 0; kt < 4; ++kt) {
                gr[u] = MFMA(Wh[0][u][kt], bh[kt], gr[u]);
                gz[u] = MFMA(Wh[1][u][kt], bh[kt], gz[u]);
            }
        }
        // consume accs cheaply (keeps chn/gr/gz/gn live)
        h00 = fmaf(chn[0][0] + gr[0][0] + gz[0][0], 1e-20f, h00);
        h01 = fmaf(chn[1][0] + gn[0][0] + gn[1][0], 1e-20f, h01);
#pragma unroll
        for (int u = 0; u < 2; ++u) {   // re-init via Wi chains (r14 pattern)
            gr[u] = MFMA(Wi[0][u][0], bx[0], zf);
            gr[u] = MFMA(Wi[0][u][1], bx[1], gr[u]);
            gz[u] = MFMA(Wi[1][u][0], bx[0], zf);
            gz[u] = MFMA(Wi[1][u][1], bx[1], gz[u]);
            gn[u] = MFMA(Wi[2][u][0], bx[0], zf);
            gn[u] = MFMA(Wi[2][u][1], bx[1], gn[u]);
        }
        lgkm_barrier();
    }
    ws[(size_t)blockIdx.x * 256 + tid] = h00 + h01;
}

// ---- iso_gate: 4-feature gate math + h ds_writes per step ----
__global__ __launch_bounds__(256, 1)
void iso_gate(float* __restrict__ ws, int NTV)
{
    const int tid = threadIdx.x;
    const int w   = tid >> 6;
    const int l   = tid & 63;
    const int s   = l & 15;
    const int q   = l >> 4;
    const int sq  = s & 7;
    const int hsel = s >> 3;

    __shared__ __align__(16) short h_bf[2][MSEQ * H];
    ((int*)h_bf[0])[tid] = 0; ((int*)h_bf[0])[tid + 256] = 0;

    int woff[2];
#pragma unroll
    for (int u = 0; u < 2; ++u)
        woff[u] = sq * 256 + ((((4 * w) + (2 * u) + (q >> 1)) ^ sq) << 4)
                + ((q & 1) << 3) + (hsel << 2);

    float h00 = 0.1f * (float)(l & 3), h01 = 0.05f, h10 = -0.1f, h11 = 0.2f;
    __syncthreads();

    for (int t = 0; t < NTV; ++t) {
        const int p = t & 1;
        // synthesize gate inputs from h (keeps the loop-carried dependency)
        {
            float vr0 = fmaf(h00, 1.10f, -0.2f), vr1 = fmaf(h01, 0.90f,  0.3f);
            float vz0 = fmaf(h10, 1.05f, -0.1f), vz1 = fmaf(h11, 0.95f,  0.2f);
            float vi0 = fmaf(h00, 0.97f,  0.1f), vi1 = fmaf(h01, 1.02f, -0.3f);
            float vh0 = fmaf(h10, 1.01f,  0.2f), vh1 = fmaf(h11, 0.99f, -0.1f);
            float r0 = sig_(vr0), r1 = sig_(vr1);
            float z0 = sig_(vz0), z1 = sig_(vz1);
            float n0 = tanh_(vi0 + r0 * vh0);
            float n1 = tanh_(vi1 + r1 * vh1);
            h00 = (1.0f - z0) * n0 + z0 * h00;
            h01 = (1.0f - z1) * n1 + z1 * h01;
        }
        {
            float vr0 = fmaf(h10, 1.08f, -0.2f), vr1 = fmaf(h11, 0.92f, 0.1f);
            float vz0 = fmaf(h00, 1.03f,  0.2f), vz1 = fmaf(h01, 0.96f,-0.2f);
            float vi0 = fmaf(h10, 0.98f, -0.1f), vi1 = fmaf(h11, 1.04f, 0.3f);
            float vh0 = fmaf(h00, 1.00f,  0.1f), vh1 = fmaf(h01, 1.01f,-0.2f);
            float r0 = sig_(vr0), r1 = sig_(vr1);
            float z0 = sig_(vz0), z1 = sig_(vz1);
            float n0 = tanh_(vi0 + r0 * vh0);
            float n1 = tanh_(vi1 + r1 * vh1);
            h10 = (1.0f - z0) * n0 + z0 * h10;
            h11 = (1.0f - z1) * n1 + z1 * h11;
        }
        *(unsigned*)((char*)h_bf[p ^ 1] + woff[0]) = cvtpk(h00, h01);
        *(unsigned*)((char*)h_bf[p ^ 1] + woff[1]) = cvtpk(h10, h11);
        lgkm_barrier();
    }
    ws[(size_t)blockIdx.x * 256 + tid] = h00 + h01 + h10 + h11
                                       + (float)h_bf[0][tid & 1023] * 1e-20f;
}

// ---- iso_ds: 6 ds_read_b128 + staging writes + global x load per step ----
__global__ __launch_bounds__(256, 1)
void iso_ds(const float* __restrict__ x,
            const int* __restrict__ offsets,
            float* __restrict__ ws, int B, int T, int NTV)
{
    const int tid = threadIdx.x;
    const int w   = tid >> 6;
    const int l   = tid & 63;
    const int s   = l & 15;
    const int q   = l >> 4;
    const int sq  = s & 7;
    const int hsel = s >> 3;

    __shared__ __align__(16) short h_bf[2][MSEQ * H];
    __shared__ __align__(16) short x_bf[2][MSEQ * D];
    __shared__ int sstart[MSEQ], slen[MSEQ];

    if (tid < MSEQ) {
        int sg = blockIdx.x * MSEQ + tid;
        int st = 0, en = 1;
        if (sg < B) { st = offsets[sg]; en = (sg + 1 < B) ? offsets[sg + 1] : T; }
        int ln = en - st;
        sstart[tid] = st; slen[tid] = max(1, min(ln, MAXLEN));
    }
    ((int*)h_bf[0])[tid] = 0; ((int*)h_bf[0])[tid + 256] = 0;
    ((int*)x_bf[0])[tid] = 0;
    __syncthreads();

    int hoff[4], xoff[2], woff[2];
#pragma unroll
    for (int kt = 0; kt < 4; ++kt) hoff[kt] = sq * 256 + (((kt * 4 + q) ^ sq) << 4);
#pragma unroll
    for (int kt = 0; kt < 2; ++kt) xoff[kt] = sq * 128 + (((kt * 4 + q) ^ sq) << 4);
#pragma unroll
    for (int u = 0; u < 2; ++u)
        woff[u] = sq * 256 + ((((4 * w) + (2 * u) + (q >> 1)) ^ sq) << 4)
                + ((q & 1) << 3) + (hsel << 2);

    const int ss  = tid >> 5;
    const int pxx = tid & 31;
    const int st_x = sstart[ss];
    const int ln_x = slen[ss];
    const float* xg = x + (size_t)st_x * D + pxx * 2;
    const int xwoff = ss * 128 + (((pxx >> 2) ^ ss) << 4) + ((pxx & 3) << 2);

    float2 xpf = *(const float2*)xg;
    unsigned snk = 1;

    for (int t = 0; t < NTV; ++t) {
        const int p = t & 1;
        const char* hb = (const char*)h_bf[p];
        const char* xb = (const char*)x_bf[p ^ 1];

        short8 bh[4], bxn[2];
#pragma unroll
        for (int kt = 0; kt < 4; ++kt) bh[kt] = *(const short8*)(hb + hoff[kt]);
#pragma unroll
        for (int kt = 0; kt < 2; ++kt) bxn[kt] = *(const short8*)(xb + xoff[kt]);

        // consume reads; write values depend on reads (realistic ordering)
        snk ^= (unsigned)(unsigned short)bh[0][0] ^ ((unsigned)(unsigned short)bh[1][1] << 8)
             ^ ((unsigned)(unsigned short)bh[2][2] << 16) ^ ((unsigned)(unsigned short)bh[3][3] << 4)
             ^ (unsigned)(unsigned short)bxn[0][0] ^ ((unsigned)(unsigned short)bxn[1][1] << 12);

        *(unsigned*)((char*)h_bf[p ^ 1] + woff[0]) = snk;
        *(unsigned*)((char*)h_bf[p ^ 1] + woff[1]) = snk ^ 0x5a5au;
        *(unsigned*)((char*)x_bf[p] + xwoff) = cvtpk(xpf.x, xpf.y);
        {
            const int tn = (t + 3 < ln_x) ? t + 3 : ln_x - 1;
            xpf = *(const float2*)(xg + (size_t)tn * D);
        }
        lgkm_barrier();
    }
    ws[(size_t)blockIdx.x * 256 + tid] = (float)snk * 1e-20f + xpf.x;
}

extern "C" void kernel_launch(void* const* d_in, const int* in_sizes, int n_in,
                              void* d_out, int out_size, void* d_ws, size_t ws_size,
                              hipStream_t stream) {
    const float* x       = (const float*)d_in[0];
    const int*   offsets = (const int*)d_in[1];
    const float* W_ih    = (const float*)d_in[2];
    const float* W_hh    = (const float*)d_in[3];
    const float* W_dense = (const float*)d_in[4];
    const float* b_dense = (const float*)d_in[5];
    float*       out     = (float*)d_out;

    const int B = in_sizes[1];
    const int T = in_sizes[0] / D;
    const int grid = (B + MSEQ - 1) / MSEQ;

    // real kernel (writes d_out, verified r14)
    gru_p4<<<grid, 256, 0, stream>>>(x, offsets, W_ih, W_hh, W_dense, b_dense, out, B, T);

    // isolation dispatches (ws only) — diagnostic
    if (ws_size >= (size_t)grid * 256 * 4 + 64) {
        float* ws = (float*)d_ws;
        iso_mfma<<<grid, 256, 0, stream>>>(W_ih, W_hh, ws, 1536);
        iso_gate<<<grid, 256, 0, stream>>>(ws, 3072);
        iso_ds  <<<grid, 256, 0, stream>>>(x, offsets, ws, B, T, 3072);
    }
}

// Round 17
// 339.378 us; speedup vs baseline: 16.8240x; 7.3380x over previous
//
#include <hip/hip_runtime.h>
#include <math.h>

constexpr int D = 64;      // input / output feature dim
constexpr int H = 128;     // GRU hidden dim
constexpr int MAXLEN = 512;
constexpr int MSEQ = 8;    // sequences per block (2x N-col duplication)

typedef __attribute__((ext_vector_type(8))) short short8;  // 8 bf16 = 4 VGPRs
typedef __attribute__((ext_vector_type(4))) float f32x4;   // MFMA accumulator

constexpr float LOG2E = 1.4426950408889634f;

__device__ __forceinline__ short f2bf(float f) {           // f32 -> bf16 RNE
    unsigned u = __float_as_uint(f);
    u += 0x7fffu + ((u >> 16) & 1u);
    return (short)(u >> 16);
}
__device__ __forceinline__ unsigned cvtpk(float a, float b) {
    unsigned r;
    asm volatile("v_cvt_pk_bf16_f32 %0, %1, %2" : "=v"(r) : "v"(a), "v"(b));
    return r;
}
// scaled pack: weights pre-multiplied so MFMA emits exp2-ready gate args
__device__ __forceinline__ short8 pack8s(float4 a, float4 b, float sc) {
    short8 r;
    r[0]=f2bf(a.x*sc); r[1]=f2bf(a.y*sc); r[2]=f2bf(a.z*sc); r[3]=f2bf(a.w*sc);
    r[4]=f2bf(b.x*sc); r[5]=f2bf(b.y*sc); r[6]=f2bf(b.z*sc); r[7]=f2bf(b.w*sc);
    return r;
}
__device__ __forceinline__ float rcp_(float x) { return __builtin_amdgcn_rcpf(x); }
__device__ __forceinline__ float exp2_(float x) {          // raw v_exp_f32 (D=2^S0)
    float r;
    asm("v_exp_f32 %0, %1" : "=v"(r) : "v"(x));
    return r;
}
// sigmoid from PRE-NEGATED-scaled arg: weights scaled by -log2e, so
// vneg = -log2e*v_true and sigma(v_true) = rcp(1 + 2^vneg). No negate, no mul.
__device__ __forceinline__ float sig_n(float vneg) {
    return rcp_(1.0f + exp2_(vneg));
}
// tanh from 2*log2e-scaled arg: exp(2|y|) = 2^|ys|. copysign form (verified).
__device__ __forceinline__ float tanh_s(float ys) {
    float a = fabsf(ys);
    float e = exp2_(a);
    float t = fmaf(-2.0f, rcp_(e + 1.0f), 1.0f);
    return copysignf(t, ys);
}
// lgkm-only barrier: orders LDS producer->consumer without draining vmcnt.
__device__ __forceinline__ void lgkm_barrier() {
    asm volatile("s_waitcnt lgkmcnt(0)\n\ts_barrier" ::: "memory");
}

#define MFMA(a,b,c) __builtin_amdgcn_mfma_f32_16x16x32_bf16((a),(b),(c),0,0,0)

// r14 structure verbatim (4 waves, 1 block/CU, gi pipelined, lgkm-only
// barrier) + gate-phase VALU trims:
//  * r,z weight rows scaled by -LOG2E  -> sigma = rcp(1+v_exp(v)) directly
//  * n   weight rows scaled by 2*LOG2E -> tanh's exp(2|y|) = v_exp(|ys|)
//  * h' = n + z*(h-n)  (one op fewer than (1-z)n + zh)
// Exact-math equivalent; ablation (r16) showed the gate phase is the
// dominant step cost (749 cyc/step isolated), so these target its VALU.
__global__ __launch_bounds__(256, 1)
void gru_t4(const float* __restrict__ x,
            const int* __restrict__ offsets,   // int32 (JAX x64 disabled)
            const float* __restrict__ W_ih,
            const float* __restrict__ W_hh,
            const float* __restrict__ W_dense,
            const float* __restrict__ b_dense,
            float* __restrict__ out,
            int B, int T)
{
    const int bb   = blockIdx.x;
    const int tid  = threadIdx.x;     // 0..255
    const int w    = tid >> 6;        // wave 0..3
    const int l    = tid & 63;
    const int s    = l & 15;          // MFMA m/n index
    const int q    = l >> 4;          // k-group 0..3
    const int sq   = s & 7;           // sequence within block
    const int hsel = s >> 3;          // 0/1: which feature pair per u

    __shared__ __align__(16) short h_bf[2][MSEQ * H];
    __shared__ __align__(16) short x_bf[2][MSEQ * D];
    __shared__ int slen[MSEQ], sstart[MSEQ];
    __shared__ float h_f32[MSEQ][H];

    if (tid < MSEQ) {
        int sg = bb * MSEQ + tid;
        int st = 0, en = 1;
        if (sg < B) { st = offsets[sg]; en = (sg + 1 < B) ? offsets[sg + 1] : T; }
        int ln = en - st;
        ln = max(1, min(ln, MAXLEN));
        sstart[tid] = st; slen[tid] = ln;
    }
    {
        int* hz = (int*)h_bf[0];
        hz[tid] = 0; hz[tid + 256] = 0;
    }
    __syncthreads();

    int nt = 1;
#pragma unroll
    for (int i = 0; i < MSEQ; ++i) nt = max(nt, slen[i]);

    // A-frags: weight rows in registers with gate-specific exp scaling.
    // g=0 (r): -LOG2E; g=1 (z): -LOG2E; g=2 (n): +2*LOG2E.
    short8 Wh[3][2][4];
    short8 Wi[3][2][2];
#pragma unroll
    for (int g = 0; g < 3; ++g) {
        const float sc = (g == 2) ? (2.0f * LOG2E) : (-LOG2E);
#pragma unroll
        for (int u = 0; u < 2; ++u) {
            const int grow = g * H + w * 32 + u * 16 + s;
            const float* ph = W_hh + (size_t)grow * H + q * 8;
#pragma unroll
            for (int kt = 0; kt < 4; ++kt)
                Wh[g][u][kt] = pack8s(*(const float4*)(ph + kt * 32),
                                      *(const float4*)(ph + kt * 32 + 4), sc);
            const float* pi = W_ih + (size_t)grow * D + q * 8;
#pragma unroll
            for (int kt = 0; kt < 2; ++kt)
                Wi[g][u][kt] = pack8s(*(const float4*)(pi + kt * 32),
                                      *(const float4*)(pi + kt * 32 + 4), sc);
        }
    }

    int hoff[4], xoff[2], woff[2];
#pragma unroll
    for (int kt = 0; kt < 4; ++kt) hoff[kt] = sq * 256 + (((kt * 4 + q) ^ sq) << 4);
#pragma unroll
    for (int kt = 0; kt < 2; ++kt) xoff[kt] = sq * 128 + (((kt * 4 + q) ^ sq) << 4);
#pragma unroll
    for (int u = 0; u < 2; ++u)
        woff[u] = sq * 256 + ((((4 * w) + (2 * u) + (q >> 1)) ^ sq) << 4)
                + ((q & 1) << 3) + (hsel << 2);

    const int ss  = tid >> 5;
    const int pxx = tid & 31;
    const int st_x = sstart[ss];
    const int ln_x = slen[ss];
    const float* xg = x + (size_t)st_x * D + pxx * 2;
    const int xwoff = ss * 128 + (((pxx >> 2) ^ ss) << 4) + ((pxx & 3) << 2);

    {
        float2 v0 = *(const float2*)xg;
        float2 v1 = *(const float2*)(xg + (size_t)min(1, ln_x - 1) * D);
        *(unsigned*)((char*)x_bf[0] + xwoff) = cvtpk(v0.x, v0.y);
        *(unsigned*)((char*)x_bf[1] + xwoff) = cvtpk(v1.x, v1.y);
    }
    float2 xpf = *(const float2*)(xg + (size_t)min(2, ln_x - 1) * D);

    const int ln_s = slen[sq];
    float h00 = 0.f, h01 = 0.f;
    float h10 = 0.f, h11 = 0.f;

    __syncthreads();

    const f32x4 zf = {0.f, 0.f, 0.f, 0.f};
    f32x4 gr[2], gz[2], gn[2];
    {
        short8 bx0[2];
#pragma unroll
        for (int kt = 0; kt < 2; ++kt)
            bx0[kt] = *(const short8*)((const char*)x_bf[0] + xoff[kt]);
#pragma unroll
        for (int u = 0; u < 2; ++u) {
            gr[u] = MFMA(Wi[0][u][0], bx0[0], zf);
            gr[u] = MFMA(Wi[0][u][1], bx0[1], gr[u]);
            gz[u] = MFMA(Wi[1][u][0], bx0[0], zf);
            gz[u] = MFMA(Wi[1][u][1], bx0[1], gz[u]);
            gn[u] = MFMA(Wi[2][u][0], bx0[0], zf);
            gn[u] = MFMA(Wi[2][u][1], bx0[1], gn[u]);
        }
    }
    lgkm_barrier();

    for (int t = 0; t < nt; ++t) {
        const int p = t & 1;
        const char* hb = (const char*)h_bf[p];
        const char* xb = (const char*)x_bf[p ^ 1];

        short8 bh[4], bxn[2];
#pragma unroll
        for (int kt = 0; kt < 4; ++kt) bh[kt] = *(const short8*)(hb + hoff[kt]);
#pragma unroll
        for (int kt = 0; kt < 2; ++kt) bxn[kt] = *(const short8*)(xb + xoff[kt]);

        f32x4 chn[2];
#pragma unroll
        for (int u = 0; u < 2; ++u) {
            chn[u] = MFMA(Wh[2][u][0], bh[0], zf);
#pragma unroll
            for (int kt = 1; kt < 4; ++kt) chn[u] = MFMA(Wh[2][u][kt], bh[kt], chn[u]);
#pragma unroll
            for (int kt = 0; kt < 4; ++kt) {
                gr[u] = MFMA(Wh[0][u][kt], bh[kt], gr[u]);
                gz[u] = MFMA(Wh[1][u][kt], bh[kt], gz[u]);
            }
        }

        // gate math (scaled-arg forms): r,z accs hold -log2e*arg; n accs hold
        // 2log2e*arg. sigma = rcp(1+2^vneg); tanh via 2^|ys|.
        const bool upd = (t < ln_s);
        {
            float vr0 = hsel ? gr[0][2] : gr[0][0], vr1 = hsel ? gr[0][3] : gr[0][1];
            float vz0 = hsel ? gz[0][2] : gz[0][0], vz1 = hsel ? gz[0][3] : gz[0][1];
            float vi0 = hsel ? gn[0][2] : gn[0][0], vi1 = hsel ? gn[0][3] : gn[0][1];
            float vh0 = hsel ? chn[0][2] : chn[0][0], vh1 = hsel ? chn[0][3] : chn[0][1];
            float r0 = sig_n(vr0), r1 = sig_n(vr1);
            float z0 = sig_n(vz0), z1 = sig_n(vz1);
            float n0 = tanh_s(fmaf(r0, vh0, vi0));
            float n1 = tanh_s(fmaf(r1, vh1, vi1));
            float a0 = fmaf(z0, h00 - n0, n0);   // n + z*(h-n)
            float a1 = fmaf(z1, h01 - n1, n1);
            h00 = upd ? a0 : h00;
            h01 = upd ? a1 : h01;
        }
        {
            float vr0 = hsel ? gr[1][2] : gr[1][0], vr1 = hsel ? gr[1][3] : gr[1][1];
            float vz0 = hsel ? gz[1][2] : gz[1][0], vz1 = hsel ? gz[1][3] : gz[1][1];
            float vi0 = hsel ? gn[1][2] : gn[1][0], vi1 = hsel ? gn[1][3] : gn[1][1];
            float vh0 = hsel ? chn[1][2] : chn[1][0], vh1 = hsel ? chn[1][3] : chn[1][1];
            float r0 = sig_n(vr0), r1 = sig_n(vr1);
            float z0 = sig_n(vz0), z1 = sig_n(vz1);
            float n0 = tanh_s(fmaf(r0, vh0, vi0));
            float n1 = tanh_s(fmaf(r1, vh1, vi1));
            float a0 = fmaf(z0, h10 - n0, n0);
            float a1 = fmaf(z1, h11 - n1, n1);
            h10 = upd ? a0 : h10;
            h11 = upd ? a1 : h11;
        }

        *(unsigned*)((char*)h_bf[p ^ 1] + woff[0]) = cvtpk(h00, h01);
        *(unsigned*)((char*)h_bf[p ^ 1] + woff[1]) = cvtpk(h10, h11);

#pragma unroll
        for (int u = 0; u < 2; ++u) {
            gr[u] = MFMA(Wi[0][u][0], bxn[0], zf);
            gr[u] = MFMA(Wi[0][u][1], bxn[1], gr[u]);
            gz[u] = MFMA(Wi[1][u][0], bxn[0], zf);
            gz[u] = MFMA(Wi[1][u][1], bxn[1], gz[u]);
            gn[u] = MFMA(Wi[2][u][0], bxn[0], zf);
            gn[u] = MFMA(Wi[2][u][1], bxn[1], gn[u]);
        }

        *(unsigned*)((char*)x_bf[p] + xwoff) = cvtpk(xpf.x, xpf.y);
        {
            const int tn = (t + 3 < ln_x) ? t + 3 : ln_x - 1;
            xpf = *(const float2*)(xg + (size_t)tn * D);
        }

        lgkm_barrier();
    }

    {
        float2 hv0 = { h00, h01 };
        float2 hv1 = { h10, h11 };
        *(float2*)&h_f32[sq][w * 32 + 0  + q * 4 + 2 * hsel] = hv0;
        *(float2*)&h_f32[sq][w * 32 + 16 + q * 4 + 2 * hsel] = hv1;
    }
    __syncthreads();

    {
        const int s2 = tid >> 5;
        const int cb = tid & 31;
        float acc0 = b_dense[cb];
        float acc1 = b_dense[cb + 32];
        const float* w0 = W_dense + (size_t)cb * H;
        const float* w1 = W_dense + (size_t)(cb + 32) * H;
#pragma unroll
        for (int j = 0; j < H; j += 4) {
            float4 hv = *(const float4*)&h_f32[s2][j];
            float4 a0 = *(const float4*)(w0 + j);
            float4 a1 = *(const float4*)(w1 + j);
            acc0 += hv.x*a0.x + hv.y*a0.y + hv.z*a0.z + hv.w*a0.w;
            acc1 += hv.x*a1.x + hv.y*a1.y + hv.z*a1.z + hv.w*a1.w;
        }
        float s2q = acc0 * acc0 + acc1 * acc1;
#pragma unroll
        for (int off = 16; off >= 1; off >>= 1) s2q += __shfl_xor(s2q, off);
        float invn = 1.0f / fmaxf(sqrtf(s2q), 1e-12f);
        int sg = bb * MSEQ + s2;
        if (sg < B) {
            out[(size_t)sg * D + cb]      = acc0 * invn;
            out[(size_t)sg * D + cb + 32] = acc1 * invn;
        }
    }
}

extern "C" void kernel_launch(void* const* d_in, const int* in_sizes, int n_in,
                              void* d_out, int out_size, void* d_ws, size_t ws_size,
                              hipStream_t stream) {
    const float* x       = (const float*)d_in[0];
    const int*   offsets = (const int*)d_in[1];
    const float* W_ih    = (const float*)d_in[2];
    const float* W_hh    = (const float*)d_in[3];
    const float* W_dense = (const float*)d_in[4];
    const float* b_dense = (const float*)d_in[5];
    float*       out     = (float*)d_out;

    const int B = in_sizes[1];
    const int T = in_sizes[0] / D;
    const int grid = (B + MSEQ - 1) / MSEQ;

    gru_t4<<<grid, 256, 0, stream>>>(x, offsets, W_ih, W_hh, W_dense, b_dense, out, B, T);
}